// Round 14
// baseline (178.899 us; speedup 1.0000x reference)
//
#include <hip/hip_runtime.h>
#include <cstdint>
#include <cstddef>

#define LN_EPS 1e-5f

typedef __attribute__((ext_vector_type(8))) __bf16 bf16x8;
typedef __attribute__((ext_vector_type(4))) float f32x4;

// Native f32->bf16 (RNE); compiler fuses pairs into v_cvt_pk_bf16_f32.
__device__ __forceinline__ unsigned short f2bf(float f) {
    union { __bf16 b; unsigned short u; } c;
    c.b = (__bf16)f;
    return c.u;
}

// tanh-form gelu via sigmoid: x * sigmoid(2*0.7978845608*(x + 0.044715x^3))
__device__ __forceinline__ float gelu_fast(float x) {
    const float x2 = x * x;
    const float p = fmaf(x2, 0.0356774081f, 0.7978845608f);
    const float y = x * p;
    const float e = __expf(-2.f * y);
    const float d = __builtin_amdgcn_rcpf(1.f + e);
    return x * d;
}

// Sum within each 32-lane half via DPP (VALU pipe, no LDS).
// Result valid in lanes 31 and 63 only.
__device__ __forceinline__ float half_sum_dpp(float x) {
    float r = x;
    int t;
    t = __builtin_amdgcn_update_dpp(0, __float_as_int(r), 0x111, 0xf, 0xf, true); // row_shr:1
    r += __int_as_float(t);
    t = __builtin_amdgcn_update_dpp(0, __float_as_int(r), 0x112, 0xf, 0xf, true); // row_shr:2
    r += __int_as_float(t);
    t = __builtin_amdgcn_update_dpp(0, __float_as_int(r), 0x114, 0xf, 0xf, true); // row_shr:4
    r += __int_as_float(t);
    t = __builtin_amdgcn_update_dpp(0, __float_as_int(r), 0x118, 0xf, 0xf, true); // row_shr:8
    r += __int_as_float(t);
    t = __builtin_amdgcn_update_dpp(0, __float_as_int(r), 0x142, 0xa, 0xf, true); // row_bcast:15
    r += __int_as_float(t);
    return r;
}

// Broadcast lane31's value to all lanes of each 32-lane half (1 DS op).
__device__ __forceinline__ float bcast31_half(float x) {
    return __int_as_float(__builtin_amdgcn_ds_swizzle(__float_as_int(x), 0x3E0));
}

// ---------------------------------------------------------------------------
// K0: one-time prep: w2 (128x128 f32, [k][n]) -> w2t bf16 transposed [n][k]
// ---------------------------------------------------------------------------
__global__ void k0_prep(const float* __restrict__ w2, unsigned short* __restrict__ w2t) {
    const int idx = blockIdx.x * 256 + threadIdx.x;   // 64 blocks x 256 = 16384
    const int k = idx >> 7, n = idx & 127;
    w2t[n * 128 + k] = f2bf(w2[idx]);
}

// ---------------------------------------------------------------------------
// K1 v4b (R12/R13, known-good): pair -> seq.  One block per (b,i).  Single
// pass over pair row (512x128 f32); per-row LN stats via DPP half-sums,
// direct exp, ONE ds_swizzle per row, 2-stage load prefetch.  Then proj,
// seq-LN, hi/hj GEMVs.
// ---------------------------------------------------------------------------
__global__ __launch_bounds__(512) void k1_pair2seq(
    const float* __restrict__ seq, const float* __restrict__ pair,
    const float* __restrict__ ln_p_w, const float* __restrict__ ln_p_b,
    const float* __restrict__ pool_w, const float* __restrict__ pool_b,
    const float* __restrict__ proj_w, const float* __restrict__ proj_b,
    const float* __restrict__ gate_ps, const float* __restrict__ ln_s_w,
    const float* __restrict__ ln_s_b, const float* __restrict__ w1,
    const float* __restrict__ b1,
    float* __restrict__ seq_out, float* __restrict__ hi_out,
    float* __restrict__ hj_out)
{
    const int bid = blockIdx.x;            // = b*512 + i
    const int tid = threadIdx.x;
    const int w = tid >> 6, lane = tid & 63;
    const int hl = lane & 31;              // lane within 32-lane half
    const int hsel = lane >> 5;            // which half

    __shared__ float wv[16][128];
    __shared__ float wss[16], wu[16];
    __shared__ float cc[2];
    __shared__ float pooled[128];
    __shared__ float su_s[256];
    __shared__ float sn_s[256];
    __shared__ float red[8];
    __shared__ float epart[2][256];

    const int pbase = hl * 4;
    const float4 lw = *(const float4*)(ln_p_w + pbase);
    const float4 lb = *(const float4*)(ln_p_b + pbase);
    const float4 pw = *(const float4*)(pool_w + pbase);
    const float pwl0 = lw.x * pw.x, pwl1 = lw.y * pw.y;
    const float pwl2 = lw.z * pw.z, pwl3 = lw.w * pw.w;

    // c1 = dot(ln_w, pool_w), c2 = dot(ln_b, pool_w) + pool_b
    if (tid < 64) {
        float t1 = pwl0 + pwl1 + pwl2 + pwl3;
        float t2 = lb.x * pw.x + lb.y * pw.y + lb.z * pw.z + lb.w * pw.w;
        for (int d = 1; d < 32; d <<= 1) {
            t1 += __shfl_xor(t1, d);
            t2 += __shfl_xor(t2, d);
        }
        if (lane == 0) { cc[0] = t1; cc[1] = t2 + pool_b[0]; }
    }
    __syncthreads();
    const float c1 = cc[0], c2 = cc[1];

    // ---- Phase A: single streaming pass, DPP stats + direct exp,
    //      2-stage load prefetch ----
    const float* prow = pair + (((size_t)bid) << 16);   // bid * 512 * 128
    const int jof = w * 2 + hsel;                       // half's row offset
    float s = 0.f, u = 0.f;
    float v0 = 0.f, v1 = 0.f, v2 = 0.f, v3 = 0.f;
    float4 x = *(const float4*)(prow + (size_t)jof * 128 + pbase);  // row t=0
    for (int t = 0; t < 32; ++t) {
        float4 xn = x;
        if (t < 31)   // issue next row's load before processing current
            xn = *(const float4*)(prow + (size_t)((t + 1) * 16 + jof) * 128 + pbase);
        float s1 = x.x + x.y + x.z + x.w;
        float s2 = fmaf(x.x, x.x, fmaf(x.y, x.y, fmaf(x.z, x.z, x.w * x.w)));
        float s3 = fmaf(x.x, pwl0, fmaf(x.y, pwl1, fmaf(x.z, pwl2, x.w * pwl3)));
        s1 = half_sum_dpp(s1);
        s2 = half_sum_dpp(s2);
        s3 = half_sum_dpp(s3);
        // valid on owner lanes (hl==31) only; garbage elsewhere is discarded
        const float mu = s1 * (1.f / 128.f);
        const float var = fmaf(-mu, mu, s2 * (1.f / 128.f));
        const float rstd = rsqrtf(var + LN_EPS);
        const float logit = fmaf(rstd, fmaf(-mu, c1, s3), c2);
        const float e = __expf(logit);
        const float er = e * rstd;
        s += e;                 // owner-lane accumulators
        u = fmaf(er, mu, u);
        const float erb = bcast31_half(er);   // owner's er to all 32 lanes
        v0 = fmaf(erb, x.x, v0);
        v1 = fmaf(erb, x.y, v1);
        v2 = fmaf(erb, x.z, v2);
        v3 = fmaf(erb, x.w, v3);
        x = xn;
    }
    {
        const int h = tid >> 5;   // 16 half-waves
        float4 vv = { v0, v1, v2, v3 };
        *(float4*)&wv[h][pbase] = vv;
        if (hl == 31) { wss[h] = s; wu[h] = u; }
    }
    __syncthreads();

    // ---- Phase B: combine 16 partial states (plain sums, direct exp) ----
    if (tid < 128) {
        float S = 0.f, U = 0.f, V = 0.f;
        #pragma unroll
        for (int k = 0; k < 16; ++k) {
            S += wss[k]; U += wu[k]; V += wv[k][tid];
        }
        pooled[tid] = ln_p_w[tid] * ((V - U) / S) + ln_p_b[tid];
    }
    __syncthreads();

    // ---- Phase C: seq_updated = seq + sig(gate)*(pooled @ proj_w + proj_b)
    float gps = gate_ps[0];
    gps = 1.f / (1.f + __expf(-gps));
    if (tid < 256) {
        float acc = proj_b[tid];
        #pragma unroll 8
        for (int p = 0; p < 128; ++p)
            acc = fmaf(pooled[p], proj_w[p * 256 + tid], acc);
        const size_t so = ((size_t)bid) * 256 + tid;
        const float su = seq[so] + gps * acc;
        seq_out[so] = su;
        su_s[tid] = su;
    }
    __syncthreads();

    // ---- Phase D: LN over D=256 of seq_updated ----
    if (tid < 256) {
        const float x2 = su_s[tid];
        float s1 = x2, s2 = x2 * x2;
        for (int d = 1; d < 64; d <<= 1) {
            s1 += __shfl_xor(s1, d);
            s2 += __shfl_xor(s2, d);
        }
        if (lane == 0) { red[w * 2] = s1; red[w * 2 + 1] = s2; }
    }
    __syncthreads();
    if (tid < 256) {
        const float s1 = red[0] + red[2] + red[4] + red[6];
        const float s2 = red[1] + red[3] + red[5] + red[7];
        const float mu = s1 * (1.f / 256.f);
        const float var = s2 * (1.f / 256.f) - mu * mu;
        const float rstd = rsqrtf(var + LN_EPS);
        sn_s[tid] = (su_s[tid] - mu) * rstd * ln_s_w[tid] + ln_s_b[tid];
    }
    __syncthreads();

    // ---- Phase E: hi = sn@w1[:256] + b1 ; hj = sn@w1[256:]  (k split x2) ----
    {
        const int outi = tid & 255;            // 0-127: hi, 128-255: hj
        const int kh = tid >> 8;               // k-half
        const int p = outi & 127;
        const int rowbase = (outi < 128 ? 0 : 256) + kh * 128;
        const float* wcol = w1 + rowbase * 128 + p;
        float acc = 0.f;
        #pragma unroll 8
        for (int k = 0; k < 128; ++k)
            acc = fmaf(sn_s[kh * 128 + k], wcol[k * 128], acc);
        epart[kh][outi] = acc;
    }
    __syncthreads();
    if (tid < 256) {
        const int p = tid & 127;
        const float r = epart[0][tid] + epart[1][tid];
        const size_t ho = ((size_t)bid) * 128 + p;
        if (tid < 128) hi_out[ho] = r + b1[p];   // fold b1 into hi
        else           hj_out[ho] = r;
    }
}

// ---------------------------------------------------------------------------
// K2 v8 = R8's v2 with ONE change: each block handles a j-HALF (256 rows)
// as two sequential 128-row subtiles, so the 32 KB w2 LDS stage happens
// ONCE per block instead of per tile (saves 16 DS+8 VMEM instr/thread per
// second tile and halves block count 4096->2048).  Per-subtile structure
// (stage hs -> sync -> prefetch residual -> MFMA -> epilogue) is v2
// verbatim; pre/acc registers reused across subtiles (no added state).
// ---------------------------------------------------------------------------
__global__ __launch_bounds__(512, 4) void k2_seq2pair(
    const float* __restrict__ pair, const float* __restrict__ hi,
    const float* __restrict__ hj, const unsigned short* __restrict__ w2t,
    const float* __restrict__ b2, const float* __restrict__ gate_sp,
    float* __restrict__ pair_out)
{
    const int rbid = 2047 - blockIdx.x;      // reverse of k1's streaming order
    const int jh = rbid & 1;                 // j-half (0: rows 0-255, 1: 256-511)
    const int bi = rbid >> 1;                // b*512 + i
    const int b = rbid >> 10;
    const int tid = threadIdx.x;
    const int w = tid >> 6, lane = tid & 63;
    const int l15 = lane & 15;
    const int kgrp = lane >> 4;

    __shared__ unsigned short hs[128 * 128];    // 32 KB, swizzled [j][p]
    __shared__ unsigned short w2s[128 * 128];   // 32 KB, swizzled [n][k]

    // hi row for this i: each thread only ever needs 4 fixed p's
    const float4 hiv = *(const float4*)(hi + ((size_t)bi) * 128 + (tid & 31) * 4);

    // stage w2^T (bf16) into LDS ONCE, swizzled: 4096 ushort4 / 512 threads
    {
        const ushort4* src = (const ushort4*)w2t;
        #pragma unroll
        for (int ii = 0; ii < 8; ++ii) {
            const int flat4 = ii * 512 + tid;
            const int n = flat4 >> 5;
            const int k4 = flat4 & 31;
            const ushort4 vldv = src[flat4];
            const unsigned off = (unsigned)((n * 256 + k4 * 8) ^ ((n & 7) << 4));
            *(ushort4*)((char*)w2s + off) = vldv;
        }
    }

    float gsp = gate_sp[0];
    gsp = 1.f / (1.f + __expf(-gsp));
    float b2v[8];
    #pragma unroll
    for (int nn = 0; nn < 8; ++nn) b2v[nn] = b2[nn * 16 + l15];

    for (int st = 0; st < 2; ++st) {
        const int j0 = jh * 256 + st * 128;      // subtile's j origin

        // build h tile: gelu(hi + hj) -> bf16 LDS, swizzled: 4096 float4 / 512
        const float* hjb = hj + ((size_t)(b * 512 + j0)) * 128;
        #pragma unroll
        for (int ii = 0; ii < 8; ++ii) {
            const int flat4 = ii * 512 + tid;
            const int r = flat4 >> 5;
            const int c4 = flat4 & 31;
            const float4 xv = *(const float4*)(hjb + r * 128 + c4 * 4);
            const float h0 = gelu_fast(xv.x + hiv.x);
            const float h1 = gelu_fast(xv.y + hiv.y);
            const float h2 = gelu_fast(xv.z + hiv.z);
            const float h3 = gelu_fast(xv.w + hiv.w);
            ushort4 ov = { f2bf(h0), f2bf(h1), f2bf(h2), f2bf(h3) };
            const unsigned off = (unsigned)((r * 256 + c4 * 8) ^ ((r & 7) << 4));
            *(ushort4*)((char*)hs + off) = ov;
        }
        __syncthreads();

        const size_t base = ((size_t)bi * 512 + j0);

        // prefetch pair residual into registers (in flight under MFMA)
        float pre[4][8];
        #pragma unroll
        for (int r = 0; r < 4; ++r) {
            const int row = w * 16 + kgrp * 4 + r;
            const float* pr = pair + (base + row) * 128 + l15;
            #pragma unroll
            for (int nn = 0; nn < 8; ++nn) pre[r][nn] = pr[nn * 16];
        }

        // MFMA: each wave does rows [w*16, w*16+16) x all 128 cols
        f32x4 acc[8];
        #pragma unroll
        for (int nn = 0; nn < 8; ++nn) acc[nn] = (f32x4){0.f, 0.f, 0.f, 0.f};

        #pragma unroll
        for (int ks = 0; ks < 4; ++ks) {
            const int kb = ks * 32 + kgrp * 8;
            const int row = w * 16 + l15;
            const unsigned aoff = (unsigned)((row * 256 + kb * 2) ^ ((row & 7) << 4));
            const bf16x8 af = *(const bf16x8*)((const char*)hs + aoff);
            #pragma unroll
            for (int nn = 0; nn < 8; ++nn) {
                const int col = nn * 16 + l15;
                const unsigned off = (unsigned)((col * 256 + kb * 2) ^ ((col & 7) << 4));
                const bf16x8 bf = *(const bf16x8*)((const char*)w2s + off);
                acc[nn] = __builtin_amdgcn_mfma_f32_16x16x32_bf16(af, bf, acc[nn], 0, 0, 0);
            }
        }

        // epilogue: residual add + gate + bias, nontemporal stores
        #pragma unroll
        for (int r = 0; r < 4; ++r) {
            const int row = w * 16 + kgrp * 4 + r;
            const size_t rb = (base + row) * 128 + l15;
            #pragma unroll
            for (int nn = 0; nn < 8; ++nn) {
                const size_t gi = rb + (size_t)(nn * 16);
                const float val = pre[r][nn] + gsp * (acc[nn][r] + b2v[nn]);
                __builtin_nontemporal_store(val, &pair_out[gi]);
            }
        }
        __syncthreads();   // before hs overwrite next subtile
    }
}

// ---------------------------------------------------------------------------
extern "C" void kernel_launch(void* const* d_in, const int* in_sizes, int n_in,
                              void* d_out, int out_size, void* d_ws, size_t ws_size,
                              hipStream_t stream)
{
    const float* seq     = (const float*)d_in[0];
    const float* pair    = (const float*)d_in[1];
    const float* ln_p_w  = (const float*)d_in[2];
    const float* ln_p_b  = (const float*)d_in[3];
    const float* pool_w  = (const float*)d_in[4];
    const float* pool_b  = (const float*)d_in[5];
    const float* proj_w  = (const float*)d_in[6];
    const float* proj_b  = (const float*)d_in[7];
    const float* gate_ps = (const float*)d_in[8];
    const float* ln_s_w  = (const float*)d_in[9];
    const float* ln_s_b  = (const float*)d_in[10];
    const float* w1      = (const float*)d_in[11];
    const float* b1      = (const float*)d_in[12];
    const float* w2      = (const float*)d_in[13];
    const float* b2      = (const float*)d_in[14];
    const float* gate_sp = (const float*)d_in[15];

    float* seq_out  = (float*)d_out;
    float* pair_out = seq_out + 2 * 512 * 256;

    float* hi_ws = (float*)d_ws;                         // 1024*128 f32
    float* hj_ws = hi_ws + 1024 * 128;                   // 1024*128 f32
    unsigned short* w2t = (unsigned short*)(hj_ws + 1024 * 128);  // 128*128 bf16

    hipLaunchKernelGGL(k0_prep, dim3(64), dim3(256), 0, stream, w2, w2t);
    hipLaunchKernelGGL(k1_pair2seq, dim3(1024), dim3(512), 0, stream,
        seq, pair, ln_p_w, ln_p_b, pool_w, pool_b, proj_w, proj_b,
        gate_ps, ln_s_w, ln_s_b, w1, b1, seq_out, hi_ws, hj_ws);
    hipLaunchKernelGGL(k2_seq2pair, dim3(2048), dim3(512), 0, stream,
        pair, hi_ws, hj_ws, w2t, b2, gate_sp, pair_out);
}

// Round 15
// 153.788 us; speedup vs baseline: 1.1633x; 1.1633x over previous
//
#include <hip/hip_runtime.h>
#include <cstdint>
#include <cstddef>

#define LN_EPS 1e-5f

typedef __attribute__((ext_vector_type(8))) __bf16 bf16x8;
typedef __attribute__((ext_vector_type(4))) float f32x4;

// Native f32->bf16 (RNE). Compiler fuses adjacent pairs into
// v_cvt_pk_bf16_f32 (1 instr / 2 values) -- do NOT hand-roll the rounding.
__device__ __forceinline__ unsigned short f2bf(float f) {
    union { __bf16 b; unsigned short u; } c;
    c.b = (__bf16)f;
    return c.u;
}

// tanh-form gelu via sigmoid: x * sigmoid(2*0.7978845608*(x + 0.044715x^3))
__device__ __forceinline__ float gelu_fast(float x) {
    const float x2 = x * x;
    const float p = fmaf(x2, 0.0356774081f, 0.7978845608f);
    const float y = x * p;
    const float e = __expf(-2.f * y);
    const float d = __builtin_amdgcn_rcpf(1.f + e);
    return x * d;
}

// Sum within each 32-lane half via DPP (VALU pipe, no LDS).
// Result valid in lanes 31 and 63 only.
__device__ __forceinline__ float half_sum_dpp(float x) {
    float r = x;
    int t;
    t = __builtin_amdgcn_update_dpp(0, __float_as_int(r), 0x111, 0xf, 0xf, true); // row_shr:1
    r += __int_as_float(t);
    t = __builtin_amdgcn_update_dpp(0, __float_as_int(r), 0x112, 0xf, 0xf, true); // row_shr:2
    r += __int_as_float(t);
    t = __builtin_amdgcn_update_dpp(0, __float_as_int(r), 0x114, 0xf, 0xf, true); // row_shr:4
    r += __int_as_float(t);
    t = __builtin_amdgcn_update_dpp(0, __float_as_int(r), 0x118, 0xf, 0xf, true); // row_shr:8
    r += __int_as_float(t);
    t = __builtin_amdgcn_update_dpp(0, __float_as_int(r), 0x142, 0xa, 0xf, true); // row_bcast:15
    r += __int_as_float(t);
    return r;
}

// Broadcast lane31's value to all lanes of each 32-lane half (1 DS op).
__device__ __forceinline__ float bcast31_half(float x) {
    return __int_as_float(__builtin_amdgcn_ds_swizzle(__float_as_int(x), 0x3E0));
}

// ---------------------------------------------------------------------------
// K0: one-time prep: w2 (128x128 f32, [k][n]) -> w2t bf16 transposed [n][k]
// ---------------------------------------------------------------------------
__global__ void k0_prep(const float* __restrict__ w2, unsigned short* __restrict__ w2t) {
    const int idx = blockIdx.x * 256 + threadIdx.x;   // 64 blocks x 256 = 16384
    const int k = idx >> 7, n = idx & 127;
    w2t[n * 128 + k] = f2bf(w2[idx]);
}

// ---------------------------------------------------------------------------
// K1 v4b (best-measured): pair -> seq.  One block per (b,i).  Single pass
// over pair row (512x128 f32); per-row LN stats via DPP half-sums, direct
// exp, ONE ds_swizzle per row, 2-stage load prefetch.  Then proj, seq-LN,
// hi/hj GEMVs.
// ---------------------------------------------------------------------------
__global__ __launch_bounds__(512) void k1_pair2seq(
    const float* __restrict__ seq, const float* __restrict__ pair,
    const float* __restrict__ ln_p_w, const float* __restrict__ ln_p_b,
    const float* __restrict__ pool_w, const float* __restrict__ pool_b,
    const float* __restrict__ proj_w, const float* __restrict__ proj_b,
    const float* __restrict__ gate_ps, const float* __restrict__ ln_s_w,
    const float* __restrict__ ln_s_b, const float* __restrict__ w1,
    const float* __restrict__ b1,
    float* __restrict__ seq_out, float* __restrict__ hi_out,
    float* __restrict__ hj_out)
{
    const int bid = blockIdx.x;            // = b*512 + i
    const int tid = threadIdx.x;
    const int w = tid >> 6, lane = tid & 63;
    const int hl = lane & 31;              // lane within 32-lane half
    const int hsel = lane >> 5;            // which half

    __shared__ float wv[16][128];
    __shared__ float wss[16], wu[16];
    __shared__ float cc[2];
    __shared__ float pooled[128];
    __shared__ float su_s[256];
    __shared__ float sn_s[256];
    __shared__ float red[8];
    __shared__ float epart[2][256];

    const int pbase = hl * 4;
    const float4 lw = *(const float4*)(ln_p_w + pbase);
    const float4 lb = *(const float4*)(ln_p_b + pbase);
    const float4 pw = *(const float4*)(pool_w + pbase);
    const float pwl0 = lw.x * pw.x, pwl1 = lw.y * pw.y;
    const float pwl2 = lw.z * pw.z, pwl3 = lw.w * pw.w;

    // c1 = dot(ln_w, pool_w), c2 = dot(ln_b, pool_w) + pool_b
    if (tid < 64) {
        float t1 = pwl0 + pwl1 + pwl2 + pwl3;
        float t2 = lb.x * pw.x + lb.y * pw.y + lb.z * pw.z + lb.w * pw.w;
        for (int d = 1; d < 32; d <<= 1) {
            t1 += __shfl_xor(t1, d);
            t2 += __shfl_xor(t2, d);
        }
        if (lane == 0) { cc[0] = t1; cc[1] = t2 + pool_b[0]; }
    }
    __syncthreads();
    const float c1 = cc[0], c2 = cc[1];

    // ---- Phase A: single streaming pass, DPP stats + direct exp,
    //      2-stage load prefetch ----
    const float* prow = pair + (((size_t)bid) << 16);   // bid * 512 * 128
    const int jof = w * 2 + hsel;                       // half's row offset
    float s = 0.f, u = 0.f;
    float v0 = 0.f, v1 = 0.f, v2 = 0.f, v3 = 0.f;
    float4 x = *(const float4*)(prow + (size_t)jof * 128 + pbase);  // row t=0
    for (int t = 0; t < 32; ++t) {
        float4 xn = x;
        if (t < 31)   // issue next row's load before processing current
            xn = *(const float4*)(prow + (size_t)((t + 1) * 16 + jof) * 128 + pbase);
        float s1 = x.x + x.y + x.z + x.w;
        float s2 = fmaf(x.x, x.x, fmaf(x.y, x.y, fmaf(x.z, x.z, x.w * x.w)));
        float s3 = fmaf(x.x, pwl0, fmaf(x.y, pwl1, fmaf(x.z, pwl2, x.w * pwl3)));
        s1 = half_sum_dpp(s1);
        s2 = half_sum_dpp(s2);
        s3 = half_sum_dpp(s3);
        // valid on owner lanes (hl==31) only; garbage elsewhere is discarded
        const float mu = s1 * (1.f / 128.f);
        const float var = fmaf(-mu, mu, s2 * (1.f / 128.f));
        const float rstd = rsqrtf(var + LN_EPS);
        const float logit = fmaf(rstd, fmaf(-mu, c1, s3), c2);
        const float e = __expf(logit);
        const float er = e * rstd;
        s += e;                 // owner-lane accumulators
        u = fmaf(er, mu, u);
        const float erb = bcast31_half(er);   // owner's er to all 32 lanes
        v0 = fmaf(erb, x.x, v0);
        v1 = fmaf(erb, x.y, v1);
        v2 = fmaf(erb, x.z, v2);
        v3 = fmaf(erb, x.w, v3);
        x = xn;
    }
    {
        const int h = tid >> 5;   // 16 half-waves
        float4 vv = { v0, v1, v2, v3 };
        *(float4*)&wv[h][pbase] = vv;
        if (hl == 31) { wss[h] = s; wu[h] = u; }
    }
    __syncthreads();

    // ---- Phase B: combine 16 partial states (plain sums, direct exp) ----
    if (tid < 128) {
        float S = 0.f, U = 0.f, V = 0.f;
        #pragma unroll
        for (int k = 0; k < 16; ++k) {
            S += wss[k]; U += wu[k]; V += wv[k][tid];
        }
        pooled[tid] = ln_p_w[tid] * ((V - U) / S) + ln_p_b[tid];
    }
    __syncthreads();

    // ---- Phase C: seq_updated = seq + sig(gate)*(pooled @ proj_w + proj_b)
    float gps = gate_ps[0];
    gps = 1.f / (1.f + __expf(-gps));
    if (tid < 256) {
        float acc = proj_b[tid];
        #pragma unroll 8
        for (int p = 0; p < 128; ++p)
            acc = fmaf(pooled[p], proj_w[p * 256 + tid], acc);
        const size_t so = ((size_t)bid) * 256 + tid;
        const float su = seq[so] + gps * acc;
        seq_out[so] = su;
        su_s[tid] = su;
    }
    __syncthreads();

    // ---- Phase D: LN over D=256 of seq_updated ----
    if (tid < 256) {
        const float x2 = su_s[tid];
        float s1 = x2, s2 = x2 * x2;
        for (int d = 1; d < 64; d <<= 1) {
            s1 += __shfl_xor(s1, d);
            s2 += __shfl_xor(s2, d);
        }
        if (lane == 0) { red[w * 2] = s1; red[w * 2 + 1] = s2; }
    }
    __syncthreads();
    if (tid < 256) {
        const float s1 = red[0] + red[2] + red[4] + red[6];
        const float s2 = red[1] + red[3] + red[5] + red[7];
        const float mu = s1 * (1.f / 256.f);
        const float var = s2 * (1.f / 256.f) - mu * mu;
        const float rstd = rsqrtf(var + LN_EPS);
        sn_s[tid] = (su_s[tid] - mu) * rstd * ln_s_w[tid] + ln_s_b[tid];
    }
    __syncthreads();

    // ---- Phase E: hi = sn@w1[:256] + b1 ; hj = sn@w1[256:]  (k split x2) ----
    {
        const int outi = tid & 255;            // 0-127: hi, 128-255: hj
        const int kh = tid >> 8;               // k-half
        const int p = outi & 127;
        const int rowbase = (outi < 128 ? 0 : 256) + kh * 128;
        const float* wcol = w1 + rowbase * 128 + p;
        float acc = 0.f;
        #pragma unroll 8
        for (int k = 0; k < 128; ++k)
            acc = fmaf(sn_s[kh * 128 + k], wcol[k * 128], acc);
        epart[kh][outi] = acc;
    }
    __syncthreads();
    if (tid < 256) {
        const int p = tid & 127;
        const float r = epart[0][tid] + epart[1][tid];
        const size_t ho = ((size_t)bid) * 128 + p;
        if (tid < 128) hi_out[ho] = r + b1[p];   // fold b1 into hi
        else           hj_out[ho] = r;
    }
}

// ---------------------------------------------------------------------------
// K2 (R8 v2, best-measured): pair_out = pair + sig(gate)*(gelu(hi+hj)@w2+b2).
// One block per (b,i,j-tile of 128), reversed order, 8 waves x 16 rows,
// MFMA 16x16x32, fast gelu, NT stores, residual prefetched before MFMA.
// ---------------------------------------------------------------------------
__global__ __launch_bounds__(512, 4) void k2_seq2pair(
    const float* __restrict__ pair, const float* __restrict__ hi,
    const float* __restrict__ hj, const unsigned short* __restrict__ w2t,
    const float* __restrict__ b2, const float* __restrict__ gate_sp,
    float* __restrict__ pair_out)
{
    const int rbid = 4095 - blockIdx.x;      // reverse of k1's streaming order
    const int jt = rbid & 3;
    const int bi = rbid >> 2;                // b*512 + i
    const int b = rbid >> 11;
    const int tid = threadIdx.x;
    const int w = tid >> 6, lane = tid & 63;

    __shared__ unsigned short hs[128 * 128];    // 32 KB, swizzled [j][p]
    __shared__ unsigned short w2s[128 * 128];   // 32 KB, swizzled [n][k]

    // hi row for this i: each thread only ever needs 4 fixed p's
    const float4 hiv = *(const float4*)(hi + ((size_t)bi) * 128 + (tid & 31) * 4);

    // stage w2^T (bf16) into LDS, swizzled: 4096 ushort4 / 512 threads
    {
        const ushort4* src = (const ushort4*)w2t;
        #pragma unroll
        for (int ii = 0; ii < 8; ++ii) {
            const int flat4 = ii * 512 + tid;
            const int n = flat4 >> 5;
            const int k4 = flat4 & 31;
            const ushort4 vldv = src[flat4];
            const unsigned off = (unsigned)((n * 256 + k4 * 8) ^ ((n & 7) << 4));
            *(ushort4*)((char*)w2s + off) = vldv;
        }
    }

    // build h tile: gelu(hi + hj) -> bf16 LDS, swizzled: 4096 float4 / 512
    const int j0 = jt << 7;
    const float* hjb = hj + ((size_t)(b * 512 + j0)) * 128;
    #pragma unroll
    for (int ii = 0; ii < 8; ++ii) {
        const int flat4 = ii * 512 + tid;
        const int r = flat4 >> 5;
        const int c4 = flat4 & 31;
        const float4 xv = *(const float4*)(hjb + r * 128 + c4 * 4);
        const float h0 = gelu_fast(xv.x + hiv.x);
        const float h1 = gelu_fast(xv.y + hiv.y);
        const float h2 = gelu_fast(xv.z + hiv.z);
        const float h3 = gelu_fast(xv.w + hiv.w);
        ushort4 ov = { f2bf(h0), f2bf(h1), f2bf(h2), f2bf(h3) };
        const unsigned off = (unsigned)((r * 256 + c4 * 8) ^ ((r & 7) << 4));
        *(ushort4*)((char*)hs + off) = ov;
    }
    __syncthreads();

    const int l15 = lane & 15;
    const int kgrp = lane >> 4;
    const size_t base = ((size_t)bi * 512 + j0);

    // prefetch pair residual into registers (in flight under MFMA)
    float pre[4][8];
    #pragma unroll
    for (int r = 0; r < 4; ++r) {
        const int row = w * 16 + kgrp * 4 + r;
        const float* pr = pair + (base + row) * 128 + l15;
        #pragma unroll
        for (int nn = 0; nn < 8; ++nn) pre[r][nn] = pr[nn * 16];
    }

    // MFMA: each wave does rows [w*16, w*16+16) x all 128 cols
    f32x4 acc[8];
    #pragma unroll
    for (int nn = 0; nn < 8; ++nn) acc[nn] = (f32x4){0.f, 0.f, 0.f, 0.f};

    #pragma unroll
    for (int ks = 0; ks < 4; ++ks) {
        const int kb = ks * 32 + kgrp * 8;
        const int row = w * 16 + l15;
        const unsigned aoff = (unsigned)((row * 256 + kb * 2) ^ ((row & 7) << 4));
        const bf16x8 af = *(const bf16x8*)((const char*)hs + aoff);
        #pragma unroll
        for (int nn = 0; nn < 8; ++nn) {
            const int col = nn * 16 + l15;
            const unsigned off = (unsigned)((col * 256 + kb * 2) ^ ((col & 7) << 4));
            const bf16x8 bf = *(const bf16x8*)((const char*)w2s + off);
            acc[nn] = __builtin_amdgcn_mfma_f32_16x16x32_bf16(af, bf, acc[nn], 0, 0, 0);
        }
    }

    // epilogue: residual add + gate + bias, nontemporal stores
    float gsp = gate_sp[0];
    gsp = 1.f / (1.f + __expf(-gsp));
    float b2v[8];
    #pragma unroll
    for (int nn = 0; nn < 8; ++nn) b2v[nn] = b2[nn * 16 + l15];

    #pragma unroll
    for (int r = 0; r < 4; ++r) {
        const int row = w * 16 + kgrp * 4 + r;
        const size_t rb = (base + row) * 128 + l15;
        #pragma unroll
        for (int nn = 0; nn < 8; ++nn) {
            const size_t gi = rb + (size_t)(nn * 16);
            const float val = pre[r][nn] + gsp * (acc[nn][r] + b2v[nn]);
            __builtin_nontemporal_store(val, &pair_out[gi]);
        }
    }
}

// ---------------------------------------------------------------------------
extern "C" void kernel_launch(void* const* d_in, const int* in_sizes, int n_in,
                              void* d_out, int out_size, void* d_ws, size_t ws_size,
                              hipStream_t stream)
{
    const float* seq     = (const float*)d_in[0];
    const float* pair    = (const float*)d_in[1];
    const float* ln_p_w  = (const float*)d_in[2];
    const float* ln_p_b  = (const float*)d_in[3];
    const float* pool_w  = (const float*)d_in[4];
    const float* pool_b  = (const float*)d_in[5];
    const float* proj_w  = (const float*)d_in[6];
    const float* proj_b  = (const float*)d_in[7];
    const float* gate_ps = (const float*)d_in[8];
    const float* ln_s_w  = (const float*)d_in[9];
    const float* ln_s_b  = (const float*)d_in[10];
    const float* w1      = (const float*)d_in[11];
    const float* b1      = (const float*)d_in[12];
    const float* w2      = (const float*)d_in[13];
    const float* b2      = (const float*)d_in[14];
    const float* gate_sp = (const float*)d_in[15];

    float* seq_out  = (float*)d_out;
    float* pair_out = seq_out + 2 * 512 * 256;

    float* hi_ws = (float*)d_ws;                         // 1024*128 f32
    float* hj_ws = hi_ws + 1024 * 128;                   // 1024*128 f32
    unsigned short* w2t = (unsigned short*)(hj_ws + 1024 * 128);  // 128*128 bf16

    hipLaunchKernelGGL(k0_prep, dim3(64), dim3(256), 0, stream, w2, w2t);
    hipLaunchKernelGGL(k1_pair2seq, dim3(1024), dim3(512), 0, stream,
        seq, pair, ln_p_w, ln_p_b, pool_w, pool_b, proj_w, proj_b,
        gate_ps, ln_s_w, ln_s_b, w1, b1, seq_out, hi_ws, hj_ws);
    hipLaunchKernelGGL(k2_seq2pair, dim3(4096), dim3(512), 0, stream,
        pair, hi_ws, hj_ws, w2t, b2, gate_sp, pair_out);
}

// Round 16
// 149.403 us; speedup vs baseline: 1.1974x; 1.0294x over previous
//
#include <hip/hip_runtime.h>
#include <cstdint>
#include <cstddef>

#define LN_EPS 1e-5f

typedef __attribute__((ext_vector_type(8))) __bf16 bf16x8;
typedef __attribute__((ext_vector_type(4))) float f32x4;

// Native f32->bf16 (RNE). Compiler fuses adjacent pairs into
// v_cvt_pk_bf16_f32 (1 instr / 2 values) -- do NOT hand-roll the rounding.
__device__ __forceinline__ unsigned short f2bf(float f) {
    union { __bf16 b; unsigned short u; } c;
    c.b = (__bf16)f;
    return c.u;
}

// tanh-form gelu via sigmoid: x * sigmoid(2*0.7978845608*(x + 0.044715x^3))
__device__ __forceinline__ float gelu_fast(float x) {
    const float x2 = x * x;
    const float p = fmaf(x2, 0.0356774081f, 0.7978845608f);
    const float y = x * p;
    const float e = __expf(-2.f * y);
    const float d = __builtin_amdgcn_rcpf(1.f + e);
    return x * d;
}

// Sum within each 32-lane half via DPP (VALU pipe, no LDS).
// Result valid in lanes 31 and 63 only.
__device__ __forceinline__ float half_sum_dpp(float x) {
    float r = x;
    int t;
    t = __builtin_amdgcn_update_dpp(0, __float_as_int(r), 0x111, 0xf, 0xf, true); // row_shr:1
    r += __int_as_float(t);
    t = __builtin_amdgcn_update_dpp(0, __float_as_int(r), 0x112, 0xf, 0xf, true); // row_shr:2
    r += __int_as_float(t);
    t = __builtin_amdgcn_update_dpp(0, __float_as_int(r), 0x114, 0xf, 0xf, true); // row_shr:4
    r += __int_as_float(t);
    t = __builtin_amdgcn_update_dpp(0, __float_as_int(r), 0x118, 0xf, 0xf, true); // row_shr:8
    r += __int_as_float(t);
    t = __builtin_amdgcn_update_dpp(0, __float_as_int(r), 0x142, 0xa, 0xf, true); // row_bcast:15
    r += __int_as_float(t);
    return r;
}

// Broadcast lane31's value to all lanes of each 32-lane half (1 DS op).
__device__ __forceinline__ float bcast31_half(float x) {
    return __int_as_float(__builtin_amdgcn_ds_swizzle(__float_as_int(x), 0x3E0));
}

// ---------------------------------------------------------------------------
// K1 v4c: pair -> seq.  One block per (b,i).  Single pass over pair row
// (512x128 f32); per-row LN stats via DPP half-sums, direct exp, ONE
// ds_swizzle per row, 2-stage load prefetch.  Then proj, seq-LN, hi/hj
// GEMVs.  Blocks 0..31 additionally transpose w2 -> w2t bf16 (k0 folded in;
// consumer k2 launches after k1 completes, so ordering is safe).
// ---------------------------------------------------------------------------
__global__ __launch_bounds__(512) void k1_pair2seq(
    const float* __restrict__ seq, const float* __restrict__ pair,
    const float* __restrict__ ln_p_w, const float* __restrict__ ln_p_b,
    const float* __restrict__ pool_w, const float* __restrict__ pool_b,
    const float* __restrict__ proj_w, const float* __restrict__ proj_b,
    const float* __restrict__ gate_ps, const float* __restrict__ ln_s_w,
    const float* __restrict__ ln_s_b, const float* __restrict__ w1,
    const float* __restrict__ b1, const float* __restrict__ w2,
    float* __restrict__ seq_out, float* __restrict__ hi_out,
    float* __restrict__ hj_out, unsigned short* __restrict__ w2t)
{
    const int bid = blockIdx.x;            // = b*512 + i
    const int tid = threadIdx.x;
    const int w = tid >> 6, lane = tid & 63;
    const int hl = lane & 31;              // lane within 32-lane half
    const int hsel = lane >> 5;            // which half

    // folded k0: w2 (128x128 f32 [k][n]) -> w2t bf16 transposed [n][k]
    if (bid < 32) {
        const int idx = bid * 512 + tid;
        const int k = idx >> 7, n = idx & 127;
        w2t[n * 128 + k] = f2bf(w2[idx]);
    }

    __shared__ float wv[16][128];
    __shared__ float wss[16], wu[16];
    __shared__ float cc[2];
    __shared__ float pooled[128];
    __shared__ float su_s[256];
    __shared__ float sn_s[256];
    __shared__ float red[8];
    __shared__ float epart[2][256];

    const int pbase = hl * 4;
    const float4 lw = *(const float4*)(ln_p_w + pbase);
    const float4 lb = *(const float4*)(ln_p_b + pbase);
    const float4 pw = *(const float4*)(pool_w + pbase);
    const float pwl0 = lw.x * pw.x, pwl1 = lw.y * pw.y;
    const float pwl2 = lw.z * pw.z, pwl3 = lw.w * pw.w;

    // c1 = dot(ln_w, pool_w), c2 = dot(ln_b, pool_w) + pool_b
    if (tid < 64) {
        float t1 = pwl0 + pwl1 + pwl2 + pwl3;
        float t2 = lb.x * pw.x + lb.y * pw.y + lb.z * pw.z + lb.w * pw.w;
        for (int d = 1; d < 32; d <<= 1) {
            t1 += __shfl_xor(t1, d);
            t2 += __shfl_xor(t2, d);
        }
        if (lane == 0) { cc[0] = t1; cc[1] = t2 + pool_b[0]; }
    }
    __syncthreads();
    const float c1 = cc[0], c2 = cc[1];

    // ---- Phase A: single streaming pass, DPP stats + direct exp,
    //      2-stage load prefetch ----
    const float* prow = pair + (((size_t)bid) << 16);   // bid * 512 * 128
    const int jof = w * 2 + hsel;                       // half's row offset
    float s = 0.f, u = 0.f;
    float v0 = 0.f, v1 = 0.f, v2 = 0.f, v3 = 0.f;
    float4 x = *(const float4*)(prow + (size_t)jof * 128 + pbase);  // row t=0
    for (int t = 0; t < 32; ++t) {
        float4 xn = x;
        if (t < 31)   // issue next row's load before processing current
            xn = *(const float4*)(prow + (size_t)((t + 1) * 16 + jof) * 128 + pbase);
        float s1 = x.x + x.y + x.z + x.w;
        float s2 = fmaf(x.x, x.x, fmaf(x.y, x.y, fmaf(x.z, x.z, x.w * x.w)));
        float s3 = fmaf(x.x, pwl0, fmaf(x.y, pwl1, fmaf(x.z, pwl2, x.w * pwl3)));
        s1 = half_sum_dpp(s1);
        s2 = half_sum_dpp(s2);
        s3 = half_sum_dpp(s3);
        // valid on owner lanes (hl==31) only; garbage elsewhere is discarded
        const float mu = s1 * (1.f / 128.f);
        const float var = fmaf(-mu, mu, s2 * (1.f / 128.f));
        const float rstd = rsqrtf(var + LN_EPS);
        const float logit = fmaf(rstd, fmaf(-mu, c1, s3), c2);
        const float e = __expf(logit);
        const float er = e * rstd;
        s += e;                 // owner-lane accumulators
        u = fmaf(er, mu, u);
        const float erb = bcast31_half(er);   // owner's er to all 32 lanes
        v0 = fmaf(erb, x.x, v0);
        v1 = fmaf(erb, x.y, v1);
        v2 = fmaf(erb, x.z, v2);
        v3 = fmaf(erb, x.w, v3);
        x = xn;
    }
    {
        const int h = tid >> 5;   // 16 half-waves
        float4 vv = { v0, v1, v2, v3 };
        *(float4*)&wv[h][pbase] = vv;
        if (hl == 31) { wss[h] = s; wu[h] = u; }
    }
    __syncthreads();

    // ---- Phase B: combine 16 partial states (plain sums, direct exp) ----
    if (tid < 128) {
        float S = 0.f, U = 0.f, V = 0.f;
        #pragma unroll
        for (int k = 0; k < 16; ++k) {
            S += wss[k]; U += wu[k]; V += wv[k][tid];
        }
        pooled[tid] = ln_p_w[tid] * ((V - U) / S) + ln_p_b[tid];
    }
    __syncthreads();

    // ---- Phase C: seq_updated = seq + sig(gate)*(pooled @ proj_w + proj_b)
    float gps = gate_ps[0];
    gps = 1.f / (1.f + __expf(-gps));
    if (tid < 256) {
        float acc = proj_b[tid];
        #pragma unroll 8
        for (int p = 0; p < 128; ++p)
            acc = fmaf(pooled[p], proj_w[p * 256 + tid], acc);
        const size_t so = ((size_t)bid) * 256 + tid;
        const float su = seq[so] + gps * acc;
        seq_out[so] = su;
        su_s[tid] = su;
    }
    __syncthreads();

    // ---- Phase D: LN over D=256 of seq_updated ----
    if (tid < 256) {
        const float x2 = su_s[tid];
        float s1 = x2, s2 = x2 * x2;
        for (int d = 1; d < 64; d <<= 1) {
            s1 += __shfl_xor(s1, d);
            s2 += __shfl_xor(s2, d);
        }
        if (lane == 0) { red[w * 2] = s1; red[w * 2 + 1] = s2; }
    }
    __syncthreads();
    if (tid < 256) {
        const float s1 = red[0] + red[2] + red[4] + red[6];
        const float s2 = red[1] + red[3] + red[5] + red[7];
        const float mu = s1 * (1.f / 256.f);
        const float var = s2 * (1.f / 256.f) - mu * mu;
        const float rstd = rsqrtf(var + LN_EPS);
        sn_s[tid] = (su_s[tid] - mu) * rstd * ln_s_w[tid] + ln_s_b[tid];
    }
    __syncthreads();

    // ---- Phase E: hi = sn@w1[:256] + b1 ; hj = sn@w1[256:]  (k split x2) ----
    {
        const int outi = tid & 255;            // 0-127: hi, 128-255: hj
        const int kh = tid >> 8;               // k-half
        const int p = outi & 127;
        const int rowbase = (outi < 128 ? 0 : 256) + kh * 128;
        const float* wcol = w1 + rowbase * 128 + p;
        float acc = 0.f;
        #pragma unroll 8
        for (int k = 0; k < 128; ++k)
            acc = fmaf(sn_s[kh * 128 + k], wcol[k * 128], acc);
        epart[kh][outi] = acc;
    }
    __syncthreads();
    if (tid < 256) {
        const int p = tid & 127;
        const float r = epart[0][tid] + epart[1][tid];
        const size_t ho = ((size_t)bid) * 128 + p;
        if (tid < 128) hi_out[ho] = r + b1[p];   // fold b1 into hi
        else           hj_out[ho] = r;
    }
}

// ---------------------------------------------------------------------------
// K2 (R8 v2, best-measured): pair_out = pair + sig(gate)*(gelu(hi+hj)@w2+b2).
// One block per (b,i,j-tile of 128), reversed order, 8 waves x 16 rows,
// MFMA 16x16x32, fast gelu, NT stores, residual prefetched before MFMA.
// ---------------------------------------------------------------------------
__global__ __launch_bounds__(512, 4) void k2_seq2pair(
    const float* __restrict__ pair, const float* __restrict__ hi,
    const float* __restrict__ hj, const unsigned short* __restrict__ w2t,
    const float* __restrict__ b2, const float* __restrict__ gate_sp,
    float* __restrict__ pair_out)
{
    const int rbid = 4095 - blockIdx.x;      // reverse of k1's streaming order
    const int jt = rbid & 3;
    const int bi = rbid >> 2;                // b*512 + i
    const int b = rbid >> 11;
    const int tid = threadIdx.x;
    const int w = tid >> 6, lane = tid & 63;

    __shared__ unsigned short hs[128 * 128];    // 32 KB, swizzled [j][p]
    __shared__ unsigned short w2s[128 * 128];   // 32 KB, swizzled [n][k]

    // hi row for this i: each thread only ever needs 4 fixed p's
    const float4 hiv = *(const float4*)(hi + ((size_t)bi) * 128 + (tid & 31) * 4);

    // stage w2^T (bf16) into LDS, swizzled: 4096 ushort4 / 512 threads
    {
        const ushort4* src = (const ushort4*)w2t;
        #pragma unroll
        for (int ii = 0; ii < 8; ++ii) {
            const int flat4 = ii * 512 + tid;
            const int n = flat4 >> 5;
            const int k4 = flat4 & 31;
            const ushort4 vldv = src[flat4];
            const unsigned off = (unsigned)((n * 256 + k4 * 8) ^ ((n & 7) << 4));
            *(ushort4*)((char*)w2s + off) = vldv;
        }
    }

    // build h tile: gelu(hi + hj) -> bf16 LDS, swizzled: 4096 float4 / 512
    const int j0 = jt << 7;
    const float* hjb = hj + ((size_t)(b * 512 + j0)) * 128;
    #pragma unroll
    for (int ii = 0; ii < 8; ++ii) {
        const int flat4 = ii * 512 + tid;
        const int r = flat4 >> 5;
        const int c4 = flat4 & 31;
        const float4 xv = *(const float4*)(hjb + r * 128 + c4 * 4);
        const float h0 = gelu_fast(xv.x + hiv.x);
        const float h1 = gelu_fast(xv.y + hiv.y);
        const float h2 = gelu_fast(xv.z + hiv.z);
        const float h3 = gelu_fast(xv.w + hiv.w);
        ushort4 ov = { f2bf(h0), f2bf(h1), f2bf(h2), f2bf(h3) };
        const unsigned off = (unsigned)((r * 256 + c4 * 8) ^ ((r & 7) << 4));
        *(ushort4*)((char*)hs + off) = ov;
    }
    __syncthreads();

    const int l15 = lane & 15;
    const int kgrp = lane >> 4;
    const size_t base = ((size_t)bi * 512 + j0);

    // prefetch pair residual into registers (in flight under MFMA)
    float pre[4][8];
    #pragma unroll
    for (int r = 0; r < 4; ++r) {
        const int row = w * 16 + kgrp * 4 + r;
        const float* pr = pair + (base + row) * 128 + l15;
        #pragma unroll
        for (int nn = 0; nn < 8; ++nn) pre[r][nn] = pr[nn * 16];
    }

    // MFMA: each wave does rows [w*16, w*16+16) x all 128 cols
    f32x4 acc[8];
    #pragma unroll
    for (int nn = 0; nn < 8; ++nn) acc[nn] = (f32x4){0.f, 0.f, 0.f, 0.f};

    #pragma unroll
    for (int ks = 0; ks < 4; ++ks) {
        const int kb = ks * 32 + kgrp * 8;
        const int row = w * 16 + l15;
        const unsigned aoff = (unsigned)((row * 256 + kb * 2) ^ ((row & 7) << 4));
        const bf16x8 af = *(const bf16x8*)((const char*)hs + aoff);
        #pragma unroll
        for (int nn = 0; nn < 8; ++nn) {
            const int col = nn * 16 + l15;
            const unsigned off = (unsigned)((col * 256 + kb * 2) ^ ((col & 7) << 4));
            const bf16x8 bf = *(const bf16x8*)((const char*)w2s + off);
            acc[nn] = __builtin_amdgcn_mfma_f32_16x16x32_bf16(af, bf, acc[nn], 0, 0, 0);
        }
    }

    // epilogue: residual add + gate + bias, nontemporal stores
    float gsp = gate_sp[0];
    gsp = 1.f / (1.f + __expf(-gsp));
    float b2v[8];
    #pragma unroll
    for (int nn = 0; nn < 8; ++nn) b2v[nn] = b2[nn * 16 + l15];

    #pragma unroll
    for (int r = 0; r < 4; ++r) {
        const int row = w * 16 + kgrp * 4 + r;
        const size_t rb = (base + row) * 128 + l15;
        #pragma unroll
        for (int nn = 0; nn < 8; ++nn) {
            const size_t gi = rb + (size_t)(nn * 16);
            const float val = pre[r][nn] + gsp * (acc[nn][r] + b2v[nn]);
            __builtin_nontemporal_store(val, &pair_out[gi]);
        }
    }
}

// ---------------------------------------------------------------------------
extern "C" void kernel_launch(void* const* d_in, const int* in_sizes, int n_in,
                              void* d_out, int out_size, void* d_ws, size_t ws_size,
                              hipStream_t stream)
{
    const float* seq     = (const float*)d_in[0];
    const float* pair    = (const float*)d_in[1];
    const float* ln_p_w  = (const float*)d_in[2];
    const float* ln_p_b  = (const float*)d_in[3];
    const float* pool_w  = (const float*)d_in[4];
    const float* pool_b  = (const float*)d_in[5];
    const float* proj_w  = (const float*)d_in[6];
    const float* proj_b  = (const float*)d_in[7];
    const float* gate_ps = (const float*)d_in[8];
    const float* ln_s_w  = (const float*)d_in[9];
    const float* ln_s_b  = (const float*)d_in[10];
    const float* w1      = (const float*)d_in[11];
    const float* b1      = (const float*)d_in[12];
    const float* w2      = (const float*)d_in[13];
    const float* b2      = (const float*)d_in[14];
    const float* gate_sp = (const float*)d_in[15];

    float* seq_out  = (float*)d_out;
    float* pair_out = seq_out + 2 * 512 * 256;

    float* hi_ws = (float*)d_ws;                         // 1024*128 f32
    float* hj_ws = hi_ws + 1024 * 128;                   // 1024*128 f32
    unsigned short* w2t = (unsigned short*)(hj_ws + 1024 * 128);  // 128*128 bf16

    hipLaunchKernelGGL(k1_pair2seq, dim3(1024), dim3(512), 0, stream,
        seq, pair, ln_p_w, ln_p_b, pool_w, pool_b, proj_w, proj_b,
        gate_ps, ln_s_w, ln_s_b, w1, b1, w2, seq_out, hi_ws, hj_ws, w2t);
    hipLaunchKernelGGL(k2_seq2pair, dim3(4096), dim3(512), 0, stream,
        pair, hi_ws, hj_ws, w2t, b2, gate_sp, pair_out);
}